// Round 5
// baseline (109.575 us; speedup 1.0000x reference)
//
#include <hip/hip_runtime.h>

// Batched MLP, round 5: rank-1 bias MFMA chunks + broadcast-MFMA final layer.
// One wave owns 128h x 32x; activations live in registers (permlane32_swap
// handoff). LDS holds only the current W image (36KB, 9 chunks/tile: 8 W
// K-chunks + 1 bias chunk [b_hi,b_lo,0..] consumed against a constant
// B-fragment {1,1,0,..}). Final layer: wl broadcast into all 32 A-rows ->
// 8 MFMA, D row 0 = output. No LDS bias/wl reads, no bpermute reduce.

#define IND      16
#define LWD      128
#define THREADS  256
#define PARAMS   51841

#define HID_STRIDE 36864                          // 4 tiles * 9 chunks * 1KB
#define WS_W0    (128 * 3 * HID_STRIDE)           // 14,155,776
#define WS_XI    (WS_W0 + 128 * 16384)            // + per-t {W0 hi|lo|b0|wl}
#define WS_TOTAL (WS_XI + 32 * 8192)              // + per-xtile x images

#define LDS_WL   36864                            // staged wl frags (512B)
#define LDS_BL   37376                            // bl (4B)
#define LDS_SZ   37380

typedef _Float16 f16x8 __attribute__((ext_vector_type(8)));
typedef _Float16 f16x4 __attribute__((ext_vector_type(4)));
typedef float    f32x16 __attribute__((ext_vector_type(16)));
typedef unsigned u32x2  __attribute__((ext_vector_type(2)));

union U4 { unsigned u[4]; f16x8 v; };

__device__ __forceinline__ f32x16 zero16() {
    f32x16 z;
#pragma unroll
    for (int i = 0; i < 16; ++i) z[i] = 0.0f;
    return z;
}
// tanh(x) = 1 - 2/(1+2^(2*log2e*x)); saturates correctly, no NaN.
__device__ __forceinline__ float fast_tanh(float v) {
    float e = __builtin_amdgcn_exp2f(v * 2.8853900817779268f);
    return 1.0f - 2.0f * __builtin_amdgcn_rcpf(e + 1.0f);
}
__device__ __forceinline__ unsigned pkf16(float a, float b) {  // RNE pack
    unsigned short ua = __builtin_bit_cast(unsigned short, (_Float16)a);
    unsigned short ub = __builtin_bit_cast(unsigned short, (_Float16)b);
    return (unsigned)ua | ((unsigned)ub << 16);
}
#define MFMA(A, B, C) __builtin_amdgcn_mfma_f32_32x32x16_f16((A), (B), (C), 0, 0, 0)

__device__ __forceinline__ void gload16(const void* g, void* l) {
    __builtin_amdgcn_global_load_lds(
        (const __attribute__((address_space(1))) void*)g,
        (__attribute__((address_space(3))) void*)l, 16, 0, 0);
}

__device__ __forceinline__ void conv8(const float* __restrict__ s, char* hidst, char* lodst) {
    float v[8];
    *reinterpret_cast<float4*>(v)     = *reinterpret_cast<const float4*>(s);
    *reinterpret_cast<float4*>(v + 4) = *reinterpret_cast<const float4*>(s + 4);
    f16x8 hi, lo;
#pragma unroll
    for (int i = 0; i < 8; ++i) {
        hi[i] = (_Float16)v[i];
        lo[i] = (_Float16)(v[i] - (float)hi[i]);
    }
    *reinterpret_cast<f16x8*>(hidst) = hi;
    *reinterpret_cast<f16x8*>(lodst) = lo;
}

// ---------------------------------------------------------------------------
// prep: build images in ws.
//  [0,3072):      hidden W K-chunks:  img(t,l) + ((h>>5)*9 + kc)*1024
//                                     + (kh*32 + (h&31))*16
//  [3072,3456):   hidden bias chunks (chunk index 8): [b_hi,b_lo,0x6] / zeros
//  [3456,3520):   W0 hi/lo rows:  W0(t) + h*32 + kh*16  (lo at +4096)
//  [3520,3648):   W0 bias chunk (+8192) and wl frags (+12288)
//  [3648,3664):   x hi/lo rows:   XI(xt) + r*32 (lo at +4096)
// ---------------------------------------------------------------------------
__global__ __launch_bounds__(256)
void prep_kernel(const float* __restrict__ theta, const float* __restrict__ xin,
                 char* __restrict__ ws)
{
    const int b = blockIdx.x, tid = threadIdx.x;
    if (b < 3072) {
        const int t = b / 24, rem = b % 24, li = rem >> 3, hblk = rem & 7;
        const int h  = hblk * 16 + (tid >> 4);
        const int kc = (tid >> 1) & 7, kh = tid & 1;
        const float* src = theta + (size_t)t * PARAMS + 2176 + li * 16512
                         + h * 128 + kc * 16 + kh * 8;
        float v[8];
        *reinterpret_cast<float4*>(v)     = *reinterpret_cast<const float4*>(src);
        *reinterpret_cast<float4*>(v + 4) = *reinterpret_cast<const float4*>(src + 4);
        f16x8 p;
#pragma unroll
        for (int i = 0; i < 8; ++i) p[i] = (_Float16)v[i];
        char* img = ws + (size_t)(t * 3 + li) * HID_STRIDE;
        *reinterpret_cast<f16x8*>(img + ((h >> 5) * 9 + kc) * 1024
                                      + (kh * 32 + (h & 31)) * 16) = p;
    } else if (b < 3456) {
        const int idx = b - 3072, t = idx / 3, li = idx % 3;
        const int tt = tid >> 6, l6 = tid & 63, kh = l6 >> 5, row = l6 & 31;
        f16x8 p;
#pragma unroll
        for (int i = 0; i < 8; ++i) p[i] = (_Float16)0.0f;
        if (kh == 0) {
            const float bv = theta[(size_t)t * PARAMS + 2176 + li * 16512
                                   + 16384 + tt * 32 + row];
            p[0] = (_Float16)bv;
            p[1] = (_Float16)(bv - (float)p[0]);
        }
        char* img = ws + (size_t)(t * 3 + li) * HID_STRIDE;
        *reinterpret_cast<f16x8*>(img + (tt * 9 + 8) * 1024 + l6 * 16) = p;
    } else if (b < 3520) {
        const int gid = (b - 3456) * 256 + tid;
        const int t = gid >> 7, h = gid & 127;
        const float* src = theta + (size_t)t * PARAMS + h * IND;
        char* dst = ws + WS_W0 + (size_t)t * 16384 + h * 32;
        conv8(src,     dst,      dst + 4096);
        conv8(src + 8, dst + 16, dst + 4096 + 16);
    } else if (b < 3648) {
        const int t = b - 3520;
        const float* th = theta + (size_t)t * PARAMS;
        char* base = ws + WS_W0 + (size_t)t * 16384;
        // b0 chunk
        {
            const int tt = tid >> 6, l6 = tid & 63, kh = l6 >> 5, row = l6 & 31;
            f16x8 p;
#pragma unroll
            for (int i = 0; i < 8; ++i) p[i] = (_Float16)0.0f;
            if (kh == 0) {
                const float bv = th[2048 + tt * 32 + row];
                p[0] = (_Float16)bv;
                p[1] = (_Float16)(bv - (float)p[0]);
            }
            *reinterpret_cast<f16x8*>(base + 8192 + tt * 1024 + l6 * 16) = p;
        }
        // wl frags: slot tid<32: kc=tid>>1, kh=tid&1 -> wl[kc*16+kh*8 .. +8]
        if (tid < 32) {
            const int kc = tid >> 1, kh = tid & 1;
            const float* src = th + 51712 + kc * 16 + kh * 8;
            f16x8 p;
#pragma unroll
            for (int i = 0; i < 8; ++i) p[i] = (_Float16)src[i];
            *reinterpret_cast<f16x8*>(base + 12288 + tid * 16) = p;
        }
    } else {
        const int row = (b - 3648) * 256 + tid;
        const float* src = xin + (size_t)row * IND;
        char* dst = ws + WS_XI + (size_t)(row >> 7) * 8192 + (row & 127) * 32;
        conv8(src,     dst,      dst + 4096);
        conv8(src + 8, dst + 16, dst + 4096 + 16);
    }
}

// ---------------------------------------------------------------------------
// main
// ---------------------------------------------------------------------------
__global__ __launch_bounds__(THREADS, 4)
void mlp_main(const float* __restrict__ theta, const char* __restrict__ ws,
              float* __restrict__ out)
{
    __shared__ __align__(16) char sL[LDS_SZ];

    const int tid = threadIdx.x, bid = blockIdx.x;
    const int sw  = (bid & 7) * 512 + (bid >> 3);   // XCD-bijective (4096%8==0)
    const int t   = sw >> 5, xt = sw & 31;
    const float* __restrict__ th = theta + (size_t)t * PARAMS;
    const int lane = tid & 63, w = tid >> 6, r31 = lane & 31, khalf = lane >> 5;
    const int bpa  = (lane ^ 32) << 2;
    (void)bpa;

    // constant B-fragment {k0=1, k1=1, rest 0} for the bias MFMA
    U4 ubias;
    ubias.u[0] = khalf ? 0u : 0x3C003C00u;
    ubias.u[1] = 0u; ubias.u[2] = 0u; ubias.u[3] = 0u;
    const f16x8 Bones = ubias.v;

    // ---- stage W1 image + wl frags + bl ----
    {
        const char* img = ws + (size_t)(t * 3) * HID_STRIDE;
#pragma unroll
        for (int c = 0; c < 9; ++c)
            gload16(img + (c * 4 + w) * 1024 + lane * 16, sL + (c * 4 + w) * 1024);
        if (tid < 32)
            gload16(ws + WS_W0 + (size_t)t * 16384 + 12288 + tid * 16,
                    sL + LDS_WL + tid * 16);
        if (tid == 32) *reinterpret_cast<float*>(sL + LDS_BL) = th[51840];
    }

    // ---- layer 0: acc = b0 (rank-1 MFMA) + W0(hi/lo) * x(hi/lo), K=16 ----
    f32x16 acc[4];
    {
        const char* w0i = ws + WS_W0 + (size_t)t  * 16384;
        const char* xi  = ws + WS_XI + (size_t)xt * 8192;
        const int ro = r31 * 32 + khalf * 16;
        const f16x8 B0h = *reinterpret_cast<const f16x8*>(xi + w * 1024 + ro);
        const f16x8 B0l = *reinterpret_cast<const f16x8*>(xi + 4096 + w * 1024 + ro);
#pragma unroll
        for (int tt = 0; tt < 4; ++tt) {
            f32x16 a = zero16();
            const f16x8 Ab = *reinterpret_cast<const f16x8*>(w0i + 8192 + tt * 1024 + lane * 16);
            a = MFMA(Ab, Bones, a);
            const f16x8 Ah = *reinterpret_cast<const f16x8*>(w0i + tt * 1024 + ro);
            const f16x8 Al = *reinterpret_cast<const f16x8*>(w0i + 4096 + tt * 1024 + ro);
            a = MFMA(Al, B0h, a);
            a = MFMA(Ah, B0l, a);
            a = MFMA(Ah, B0h, a);
            acc[tt] = a;
        }
    }

    f16x8 Bf[8];
    // tanh(acc) -> f16 pack -> permlane32_swap assembles next-layer B-frags.
    auto activate_pack = [&]() {
#pragma unroll
        for (int tt = 0; tt < 4; ++tt) {
            unsigned P0[4], P1[4];
#pragma unroll
            for (int g = 0; g < 4; ++g) {
                const float v0 = fast_tanh(acc[tt][4 * g + 0]);
                const float v1 = fast_tanh(acc[tt][4 * g + 1]);
                const float v2 = fast_tanh(acc[tt][4 * g + 2]);
                const float v3 = fast_tanh(acc[tt][4 * g + 3]);
                P0[g] = pkf16(v0, v1);
                P1[g] = pkf16(v2, v3);
            }
#pragma unroll
            for (int j = 0; j < 2; ++j) {        // kc = 2*tt + j
#if __has_builtin(__builtin_amdgcn_permlane32_swap)
                const u32x2 r0 = __builtin_amdgcn_permlane32_swap(
                    P0[2 * j], P0[2 * j + 1], false, false);
                const u32x2 r1 = __builtin_amdgcn_permlane32_swap(
                    P1[2 * j], P1[2 * j + 1], false, false);
                U4 u;
                u.u[0] = r0[0]; u.u[1] = r1[0]; u.u[2] = r0[1]; u.u[3] = r1[1];
#else
                const unsigned s0 = khalf ? P0[2 * j] : P0[2 * j + 1];
                const unsigned s1 = khalf ? P1[2 * j] : P1[2 * j + 1];
                const unsigned q0 = (unsigned)__builtin_amdgcn_ds_bpermute(bpa, (int)s0);
                const unsigned q1 = (unsigned)__builtin_amdgcn_ds_bpermute(bpa, (int)s1);
                U4 u;
                u.u[0] = khalf ? q0 : P0[2 * j];
                u.u[1] = khalf ? q1 : P1[2 * j];
                u.u[2] = khalf ? P0[2 * j + 1] : q0;
                u.u[3] = khalf ? P1[2 * j + 1] : q1;
#endif
                Bf[2 * tt + j] = u.v;
            }
        }
    };
    activate_pack();
    __syncthreads();            // W1 + wl + bl staged & visible

    // ---- hidden layers 1..3 ----
#pragma unroll
    for (int l = 1; l <= 3; ++l) {
        __builtin_amdgcn_s_setprio(1);
#pragma unroll
        for (int tt = 0; tt < 4; ++tt) {
            f32x16 a = zero16();
            // bias chunk (rank-1)
            a = MFMA(*reinterpret_cast<const f16x8*>(
                         sL + (tt * 9 + 8) * 1024 + lane * 16), Bones, a);
            // 8 W K-chunks; addr = one reg (lane*16) + immediates, conflict-free
#pragma unroll
            for (int kc = 0; kc < 8; ++kc) {
                const f16x8 av = *reinterpret_cast<const f16x8*>(
                    sL + (tt * 9 + kc) * 1024 + lane * 16);
                a = MFMA(av, Bf[kc], a);
            }
            acc[tt] = a;
        }
        __builtin_amdgcn_s_setprio(0);
        if (l < 3) {
            __syncthreads();    // all waves done reading W_l
            const char* img = ws + (size_t)(t * 3 + l) * HID_STRIDE;
#pragma unroll
            for (int c = 0; c < 9; ++c)
                gload16(img + (c * 4 + w) * 1024 + lane * 16, sL + (c * 4 + w) * 1024);
            activate_pack();    // VALU phase hides the stage latency
            __syncthreads();    // W_{l+1} visible (barrier drains vmcnt)
        }
    }

    // ---- final layer: wl broadcast in all A-rows -> D[r][x] = out[x] ----
    activate_pack();            // h4 -> Bf
    const float bl = *reinterpret_cast<const float*>(sL + LDS_BL);
    f32x16 af = zero16();
#pragma unroll
    for (int kc = 0; kc < 8; ++kc) {
        const f16x8 wv = *reinterpret_cast<const f16x8*>(
            sL + LDS_WL + (kc * 2 + khalf) * 16);   // uniform per khalf: broadcast
        af = MFMA(wv, Bf[kc], af);
    }
    if (!khalf) out[(size_t)t * 4096 + xt * 128 + w * 32 + r31] = af[0] + bl;
}

// ---------------------------------------------------------------------------
// Fallback (round-1 kernel, self-contained, known-good) if ws is too small.
// ---------------------------------------------------------------------------
__global__ __launch_bounds__(THREADS, 1)
void mlp_kernel_fb(const float* __restrict__ xin,
                   const float* __restrict__ theta,
                   float* __restrict__ out)
{
    __shared__ __align__(16) _Float16 sH   [128 * LWD];
    __shared__ __align__(16) _Float16 sWhi [LWD * LWD];
    __shared__ __align__(16) _Float16 sWlo [LWD * LWD];
    __shared__ __align__(16) _Float16 sX0hi[128 * IND];
    __shared__ __align__(16) _Float16 sX0lo[128 * IND];
    __shared__ __align__(16) _Float16 sW0hi[LWD * IND];
    __shared__ __align__(16) _Float16 sW0lo[LWD * IND];
    __shared__ float sB[2][LWD];
    __shared__ float sWl[LWD + 1];

    const int tid = threadIdx.x;
    const int bid = blockIdx.x;
    const int sw  = (bid & 7) * 512 + (bid >> 3);
    const int t   = sw >> 5;
    const int xt  = sw & 31;
    const float* __restrict__ th = theta + (size_t)t * PARAMS;
    const float* __restrict__ xg = xin   + (size_t)xt * (128 * IND);

#pragma unroll
    for (int j = 0; j < 2; ++j) {
        const int flat = j * 1024 + tid * 4;
        const float4 v = *reinterpret_cast<const float4*>(xg + flat);
        _Float16 h0 = (_Float16)v.x, h1 = (_Float16)v.y, h2 = (_Float16)v.z, h3 = (_Float16)v.w;
        f16x4 ph = {h0, h1, h2, h3};
        f16x4 pl = {(_Float16)(v.x - (float)h0), (_Float16)(v.y - (float)h1),
                    (_Float16)(v.z - (float)h2), (_Float16)(v.w - (float)h3)};
        *reinterpret_cast<f16x4*>(&sX0hi[flat]) = ph;
        *reinterpret_cast<f16x4*>(&sX0lo[flat]) = pl;
    }
#pragma unroll
    for (int j = 0; j < 2; ++j) {
        const int flat = j * 1024 + tid * 4;
        const float a0 = th[flat], a1 = th[flat + 1], a2 = th[flat + 2], a3 = th[flat + 3];
        _Float16 h0 = (_Float16)a0, h1 = (_Float16)a1, h2 = (_Float16)a2, h3 = (_Float16)a3;
        f16x4 ph = {h0, h1, h2, h3};
        f16x4 pl = {(_Float16)(a0 - (float)h0), (_Float16)(a1 - (float)h1),
                    (_Float16)(a2 - (float)h2), (_Float16)(a3 - (float)h3)};
        *reinterpret_cast<f16x4*>(&sW0hi[flat]) = ph;
        *reinterpret_cast<f16x4*>(&sW0lo[flat]) = pl;
    }
    if (tid < LWD) sB[0][tid] = th[IND * LWD + tid];
    __syncthreads();

    const int lane  = tid & 63;
    const int w     = tid >> 6;
    const int r31   = lane & 31;
    const int khalf = lane >> 5;
    const int hb    = (w >> 1) * 64;
    const int xb    = (w & 1) * 64;
    const int hA0 = hb + r31,  hA1 = hb + 32 + r31;
    const int xB0 = xb + r31,  xB1 = xb + 32 + r31;
    const int swzA0 = (hA0 & 15) << 4, swzA1 = (hA1 & 15) << 4;
    const int swzB0 = (xB0 & 15) << 4, swzB1 = (xB1 & 15) << 4;

    f32x16 acc[2][2];

    {
        const int kb = khalf * 16;
        f16x8 ah[2], al[2], bh[2], bl[2];
        ah[0] = *reinterpret_cast<const f16x8*>((const char*)sW0hi + hA0 * 32 + kb);
        ah[1] = *reinterpret_cast<const f16x8*>((const char*)sW0hi + hA1 * 32 + kb);
        al[0] = *reinterpret_cast<const f16x8*>((const char*)sW0lo + hA0 * 32 + kb);
        al[1] = *reinterpret_cast<const f16x8*>((const char*)sW0lo + hA1 * 32 + kb);
        bh[0] = *reinterpret_cast<const f16x8*>((const char*)sX0hi + xB0 * 32 + kb);
        bh[1] = *reinterpret_cast<const f16x8*>((const char*)sX0hi + xB1 * 32 + kb);
        bl[0] = *reinterpret_cast<const f16x8*>((const char*)sX0lo + xB0 * 32 + kb);
        bl[1] = *reinterpret_cast<const f16x8*>((const char*)sX0lo + xB1 * 32 + kb);
#pragma unroll
        for (int tt = 0; tt < 2; ++tt)
#pragma unroll
            for (int tx = 0; tx < 2; ++tx) {
                f32x16 a;
#pragma unroll
                for (int i = 0; i < 16; ++i) a[i] = 0.0f;
                a = MFMA(al[tt], bh[tx], a);
                a = MFMA(ah[tt], bl[tx], a);
                a = MFMA(ah[tt], bh[tx], a);
                acc[tt][tx] = a;
            }
    }

    auto epilogue = [&](const float* __restrict__ bb) {
#pragma unroll
        for (int tt = 0; tt < 2; ++tt)
#pragma unroll
            for (int tx = 0; tx < 2; ++tx) {
                const int xw  = xb + tx * 32 + r31;
                const int swz = (xw & 15) << 4;
#pragma unroll
                for (int g = 0; g < 4; ++g) {
                    const int hbase = hb + tt * 32 + g * 8 + khalf * 4;
                    f16x4 pk;
#pragma unroll
                    for (int q = 0; q < 4; ++q) {
                        const float v = acc[tt][tx][g * 4 + q] + bb[hbase + q];
                        pk[q] = (_Float16)(1.0f - 2.0f * __builtin_amdgcn_rcpf(
                            __builtin_amdgcn_exp2f(v * 2.8853900817779268f) + 1.0f));
                    }
                    *reinterpret_cast<f16x4*>((char*)sH + xw * 256 + ((hbase * 2) ^ swz)) = pk;
                }
            }
    };

    for (int l = 0; l < 3; ++l) {
        __syncthreads();
        const float* __restrict__ wsrc = th + 2176 + l * 16512;
#pragma unroll
        for (int j = 0; j < 16; ++j) {
            const int flat = j * 1024 + tid * 4;
            const int hrow = flat >> 7;
            const int o    = flat & 127;
            const float a0 = wsrc[flat], a1 = wsrc[flat + 1], a2 = wsrc[flat + 2], a3 = wsrc[flat + 3];
            _Float16 h0 = (_Float16)a0, h1 = (_Float16)a1, h2 = (_Float16)a2, h3 = (_Float16)a3;
            f16x4 ph = {h0, h1, h2, h3};
            f16x4 pl = {(_Float16)(a0 - (float)h0), (_Float16)(a1 - (float)h1),
                        (_Float16)(a2 - (float)h2), (_Float16)(a3 - (float)h3)};
            const int boff = hrow * 256 + ((o * 2) ^ ((hrow & 15) << 4));
            *reinterpret_cast<f16x4*>((char*)sWhi + boff) = ph;
            *reinterpret_cast<f16x4*>((char*)sWlo + boff) = pl;
        }
        if (tid < LWD) sB[(l + 1) & 1][tid] = wsrc[LWD * LWD + tid];
        if (l == 2) {
            if (tid < LWD) sWl[tid] = th[51712 + tid];
            if (tid == LWD) sWl[LWD] = th[51840];
        }

        epilogue(sB[l & 1]);
        __syncthreads();

#pragma unroll
        for (int tt = 0; tt < 2; ++tt)
#pragma unroll
            for (int tx = 0; tx < 2; ++tx)
#pragma unroll
                for (int i = 0; i < 16; ++i) acc[tt][tx][i] = 0.0f;
#pragma unroll
        for (int kc = 0; kc < 8; ++kc) {
            const int kb = kc * 32 + khalf * 16;
            f16x8 ah[2], al[2], bv[2];
            ah[0] = *reinterpret_cast<const f16x8*>((const char*)sWhi + hA0 * 256 + (kb ^ swzA0));
            ah[1] = *reinterpret_cast<const f16x8*>((const char*)sWhi + hA1 * 256 + (kb ^ swzA1));
            al[0] = *reinterpret_cast<const f16x8*>((const char*)sWlo + hA0 * 256 + (kb ^ swzA0));
            al[1] = *reinterpret_cast<const f16x8*>((const char*)sWlo + hA1 * 256 + (kb ^ swzA1));
            bv[0] = *reinterpret_cast<const f16x8*>((const char*)sH   + xB0 * 256 + (kb ^ swzB0));
            bv[1] = *reinterpret_cast<const f16x8*>((const char*)sH   + xB1 * 256 + (kb ^ swzB1));
#pragma unroll
            for (int tt = 0; tt < 2; ++tt)
#pragma unroll
                for (int tx = 0; tx < 2; ++tx) {
                    acc[tt][tx] = MFMA(al[tt], bv[tx], acc[tt][tx]);
                    acc[tt][tx] = MFMA(ah[tt], bv[tx], acc[tt][tx]);
                }
        }
    }

    __syncthreads();
    epilogue(sB[1]);
    __syncthreads();

    if (tid < 128) {
        const int r   = tid;
        const int swz = (r & 15) << 4;
        float s = 0.0f;
#pragma unroll
        for (int c = 0; c < 16; ++c) {
            const int hc = (c + r) & 15;
            const f16x8 hv = *reinterpret_cast<const f16x8*>(
                (const char*)sH + r * 256 + ((hc * 16) ^ swz));
#pragma unroll
            for (int q = 0; q < 8; ++q) s += (float)hv[q] * sWl[hc * 8 + q];
        }
        out[(size_t)t * 4096 + (size_t)xt * 128 + r] = s + sWl[LWD];
    }
}

extern "C" void kernel_launch(void* const* d_in, const int* in_sizes, int n_in,
                              void* d_out, int out_size, void* d_ws, size_t ws_size,
                              hipStream_t stream)
{
    const float* x     = (const float*)d_in[0];
    const float* theta = (const float*)d_in[1];
    float* out = (float*)d_out;

    if (ws_size >= (size_t)WS_TOTAL) {
        prep_kernel<<<dim3(3664), dim3(256), 0, stream>>>(theta, x, (char*)d_ws);
        mlp_main<<<dim3(4096), dim3(THREADS), 0, stream>>>(theta, (const char*)d_ws, out);
    } else {
        mlp_kernel_fb<<<dim3(4096), dim3(THREADS), 0, stream>>>(x, theta, out);
    }
}